// Round 4
// baseline (1219.797 us; speedup 1.0000x reference)
//
#include <hip/hip_runtime.h>

// Problem constants (fixed by the reference setup_inputs()):
//   B=4, Q_LEN=8192, K_LEN=8192, N_SEG=8, WINDOW=1024, OFFSET=0
// Harness dtype mapping (measured R2/R3): bool -> int32 on both input and
// output (absmax signature float(1.0).view(int32)-1; R3 passed with int 0/1).
#define QL 8192
#define KL 8192
#define BB 4
#define K4 (KL / 4)      // 2048 int4s per k-row
#define CHUNK 256        // int4s per chunk == block width
#define NCH (K4 / CHUNK) // 8 chunks per row

typedef int v4i __attribute__((ext_vector_type(4)));

// One 256-thread block per (b,q) row. q/b/lo/hi/qs are block-uniform (SGPR),
// so 6 of 8 chunks compile to a bare global_store_dwordx4 of zeros; only the
// <=2 chunks intersecting the 1024-wide band do loads + compares.
__global__ __launch_bounds__(256) void mask_kernel(
    const int* __restrict__ expl,     // explicit_mask [Q,K] int32 0/1
    const int* __restrict__ qseg,     // q_segment_ids [B,Q]
    const int* __restrict__ kseg,     // kv_segment_ids [B,K]
    const int* __restrict__ p_off,    // causal_offset scalar
    const int* __restrict__ p_win,    // window scalar
    int* __restrict__ out)            // [B,Q,K] int32 0/1
{
    const int row = blockIdx.x;            // b*QL + q
    const int q = row & (QL - 1);
    const int b = row >> 13;
    const int t = threadIdx.x;

    const int offset = *p_off;
    const int window = *p_win;
    const int dmin = (-offset > 0) ? -offset : 0;
    const int lo = q - (window - 1);       // band: lo <= k <= hi
    const int hi = q - dmin;
    const int qs = qseg[row];              // [b,q] flat == row

    v4i* __restrict__ orow = reinterpret_cast<v4i*>(out) + (long long)row * K4;
    const v4i* __restrict__ erow = reinterpret_cast<const v4i*>(expl) + (long long)q * K4;
    const v4i* __restrict__ srow = reinterpret_cast<const v4i*>(kseg) + b * K4;

    #pragma unroll
    for (int c = 0; c < NCH; ++c) {
        const int i4 = c * CHUNK + t;      // int4 index within the row
        const int k0 = i4 << 2;            // first k element of this int4
        v4i v = (v4i)(0);
        if (k0 + 3 >= lo && k0 <= hi) {    // uniform-false in zero chunks
            const v4i e = erow[i4];
            const v4i s = srow[i4];
            v.x = (k0     >= lo && k0     <= hi && e.x != 0 && s.x == qs) ? 1 : 0;
            v.y = (k0 + 1 >= lo && k0 + 1 <= hi && e.y != 0 && s.y == qs) ? 1 : 0;
            v.z = (k0 + 2 >= lo && k0 + 2 <= hi && e.z != 0 && s.z == qs) ? 1 : 0;
            v.w = (k0 + 3 >= lo && k0 + 3 <= hi && e.w != 0 && s.w == qs) ? 1 : 0;
        }
        orow[i4] = v;
    }
}

extern "C" void kernel_launch(void* const* d_in, const int* in_sizes, int n_in,
                              void* d_out, int out_size, void* d_ws, size_t ws_size,
                              hipStream_t stream) {
    // setup_inputs() dict order:
    //   0: explicit_mask [Q,K] (bool -> int32)
    //   1: q_segment_ids [B,Q] int32
    //   2: kv_segment_ids [B,K] int32
    //   3: q_len  4: k_len  5: causal_offset  6: window  (scalars)
    const int* expl  = (const int*)d_in[0];
    const int* qseg  = (const int*)d_in[1];
    const int* kseg  = (const int*)d_in[2];
    const int* p_off = (const int*)d_in[5];
    const int* p_win = (const int*)d_in[6];
    int* out = (int*)d_out;

    const int grid = BB * QL;              // 32768 blocks, one per (b,q) row
    mask_kernel<<<dim3(grid), dim3(256), 0, stream>>>(
        expl, qseg, kseg, p_off, p_win, out);
}

// Round 5
// 1198.818 us; speedup vs baseline: 1.0175x; 1.0175x over previous
//
#include <hip/hip_runtime.h>

// Problem constants (fixed by the reference setup_inputs()):
//   B=4, Q_LEN=8192, K_LEN=8192, N_SEG=8, WINDOW=1024, OFFSET=0
// Harness dtype mapping (measured R2/R3): bool -> int32 on input and output.
//
// Two-kernel structure (R5 experiment — disambiguate kernel time from harness
// overhead): (1) streaming zero-fill of the whole 1.07 GB output, mimicking
// __amd_rocclr_fillBufferAligned which measures 6.2 TB/s on this box;
// (2) band-only kernel touching the <=1024-wide sliding-window band per
// (b,q) row (<=257 int4s), doing the explicit/segment compares there.
#define QL 8192
#define KL 8192
#define BB 4
#define K4 (KL / 4)                 // 2048 int4s per k-row
#define TOTAL_I4 (1LL << 26)        // BB*QL*K4 = 67,108,864 int4s

typedef int v4i __attribute__((ext_vector_type(4)));

// ---- Kernel 1: zero-fill. 2^23 threads x 8 int4 stores, pass-contiguous
// (stride 2^23 int4s between a thread's stores) so every pass is a fully
// coalesced sweep. Pure store stream, ~5 VALU ops total.
__global__ __launch_bounds__(256) void zero_kernel(v4i* __restrict__ out) {
    const long long tid = (long long)blockIdx.x * 256 + threadIdx.x; // [0, 2^23)
    const v4i z = (v4i)(0);
#pragma unroll
    for (int j = 0; j < 8; ++j)
        out[tid + ((long long)j << 23)] = z;
}

// ---- Kernel 2: band fill. One block per (b,q) row; threads cover the
// int4 span [base4, hi4] (<=257 entries for window=1024). Edge int4s get
// zeros outside [lo,hi] — harmless overwrite of kernel 1's zeros.
__global__ __launch_bounds__(320) void band_kernel(
    const int* __restrict__ expl,     // explicit_mask [Q,K] int32 0/1
    const int* __restrict__ qseg,     // q_segment_ids [B,Q]
    const int* __restrict__ kseg,     // kv_segment_ids [B,K]
    const int* __restrict__ p_off,    // causal_offset scalar
    const int* __restrict__ p_win,    // window scalar
    int* __restrict__ out)            // [B,Q,K] int32 0/1
{
    const int row = blockIdx.x;            // b*QL + q
    const int q = row & (QL - 1);
    const int b = row >> 13;

    const int offset = *p_off;
    const int window = *p_win;
    const int dmin = (-offset > 0) ? -offset : 0;
    const int lo = q - (window - 1);       // band: lo <= k <= hi
    const int hi = q - dmin;
    if (hi < 0) return;                    // entire row is zero (kernel 1 did it)
    const int lo_c = lo > 0 ? lo : 0;
    const int base4 = lo_c >> 2;
    const int hi4 = hi >> 2;               // hi <= QL-1 < KL, in range

    const int qs = qseg[row];
    v4i* __restrict__ orow = reinterpret_cast<v4i*>(out) + (long long)row * K4;
    const v4i* __restrict__ erow = reinterpret_cast<const v4i*>(expl) + (long long)q * K4;
    const v4i* __restrict__ srow = reinterpret_cast<const v4i*>(kseg) + b * K4;

    for (int i4 = base4 + (int)threadIdx.x; i4 <= hi4; i4 += 320) {
        const v4i e = erow[i4];
        const v4i s = srow[i4];
        const int k0 = i4 << 2;
        v4i v;
        v.x = (k0     >= lo && k0     <= hi && e.x != 0 && s.x == qs) ? 1 : 0;
        v.y = (k0 + 1 >= lo && k0 + 1 <= hi && e.y != 0 && s.y == qs) ? 1 : 0;
        v.z = (k0 + 2 >= lo && k0 + 2 <= hi && e.z != 0 && s.z == qs) ? 1 : 0;
        v.w = (k0 + 3 >= lo && k0 + 3 <= hi && e.w != 0 && s.w == qs) ? 1 : 0;
        orow[i4] = v;
    }
}

extern "C" void kernel_launch(void* const* d_in, const int* in_sizes, int n_in,
                              void* d_out, int out_size, void* d_ws, size_t ws_size,
                              hipStream_t stream) {
    // setup_inputs() dict order:
    //   0: explicit_mask [Q,K] (bool -> int32)
    //   1: q_segment_ids [B,Q] int32
    //   2: kv_segment_ids [B,K] int32
    //   3: q_len  4: k_len  5: causal_offset  6: window  (scalars)
    const int* expl  = (const int*)d_in[0];
    const int* qseg  = (const int*)d_in[1];
    const int* kseg  = (const int*)d_in[2];
    const int* p_off = (const int*)d_in[5];
    const int* p_win = (const int*)d_in[6];
    int* out = (int*)d_out;

    // 1) zero everything: 2^23 threads / 256 = 32768 blocks
    zero_kernel<<<dim3(32768), dim3(256), 0, stream>>>(
        reinterpret_cast<v4i*>(out));
    // 2) fill the band: one block per (b,q) row, same stream (ordered)
    band_kernel<<<dim3(BB * QL), dim3(320), 0, stream>>>(
        expl, qseg, kseg, p_off, p_win, out);
}